// Round 2
// baseline (492.489 us; speedup 1.0000x reference)
//
#include <hip/hip_runtime.h>

typedef _Float16 half8 __attribute__((ext_vector_type(8)));
typedef float floatx4 __attribute__((ext_vector_type(4)));
typedef unsigned uint4v __attribute__((ext_vector_type(4)));

#define Bsz 512
#define Tsz 168
#define Fsz 16
#define Hsz 256
#define KTILES 9      // K = 288 = 9 * 32  (256 h + 16 x + 16 zero pad)
#define LDS_K 296     // padded LDS row stride in halves

// workspace layout (bytes, all 16B aligned) — prep tables gone (built in-kernel)
#define HH_OFF    675840     // h history f16 [B][T][H]: 512*168*256*2 = 44040192
#define XBUF_OFF  (HH_OFF + 44040192)   // tagged exchange ring: 32bb*2*16m*128slot*8B = 1 MB

// ---------------- recurrent LSTM v15 ---------------------------------------
// R14 post-mortem: VGPR_Count=72 proves wf[2][9] (72 VGPR alone) was NOT
// resident — __launch_bounds__(512,1) let the allocator chase occupancy we
// can never use (128 WGs on 256 CUs = 1 WG/CU) and re-load weights from L2
// every step. v15:
//  * __launch_bounds__(512,2): 8 waves = exactly 2/EU -> 256-VGPR budget,
//    weights pinned in registers.
//  * x_{t+1} prefetch ISSUED AT TOP of step (was after cell): x is a cold
//    HBM miss (~900cy) read once per step; whole step now hides it.
//  * publish-first after cell (partner-visible chain shortened).
//  * spin loop: unconditional 3-load retry (no per-atom exec-mask dance).
//  * prep folded into prologue: wf/bias built directly from w_hh/w_ih/b_*
//    (identical swizzle math to the old k_prep).
__global__ __launch_bounds__(512, 2) void k_lstm15(
    const float* __restrict__ x, const float* __restrict__ w_ih,
    const float* __restrict__ w_hh, const float* __restrict__ b_ih,
    const float* __restrict__ b_hh, unsigned* __restrict__ hh32,
    unsigned long long* __restrict__ xbuf) {
    __shared__ __align__(16) _Float16 h_lds[16][LDS_K];   // h | x | pad
    __shared__ float glds[4][16][68];                     // [gate][m][j_local], pad 68

    const int tid = threadIdx.x;
    const int wave = tid >> 6, lane = tid & 63;
    const int n_in = lane & 15, quad = lane >> 4;
    const int bb = blockIdx.x & 31, ng = blockIdx.x >> 5;   // XCD-colocated swizzle
    const int b0 = bb * 16;
    const int Jl = wave & 3;               // local J-block 0..3
    const int gp = wave >> 2;              // gate pair: 0 -> (i,f), 1 -> (g,o)
    (void)wave;

    // ---- prologue: build this wave's 18 weight B-frags + bias in VGPRs ----
    // frag[e] = w[n_orig][kt*32 + quad*8 + e], n_orig = g*256 + J*16 + n_in
    float bs[2];
    half8 wf[2][KTILES];
#pragma unroll
    for (int gg = 0; gg < 2; ++gg) {
        const int nt = ng * 16 + Jl * 4 + gp * 2 + gg;
        const int J = nt >> 2, g = nt & 3;
        const int n_orig = g * 256 + J * 16 + n_in;
        bs[gg] = b_ih[n_orig] + b_hh[n_orig];
#pragma unroll
        for (int kt = 0; kt < 8; ++kt) {
            const float* src = &w_hh[n_orig * 256 + kt * 32 + quad * 8];
            half8 v;
#pragma unroll
            for (int e = 0; e < 8; ++e) v[e] = (_Float16)src[e];
            wf[gg][kt] = v;
        }
        half8 vx;
        if (quad < 2) {
            const float* srcx = &w_ih[n_orig * 16 + quad * 8];
#pragma unroll
            for (int e = 0; e < 8; ++e) vx[e] = (_Float16)srcx[e];
        } else {
#pragma unroll
            for (int e = 0; e < 8; ++e) vx[e] = (_Float16)0.0f;
        }
        wf[gg][8] = vx;
    }

    // zero h0 + x + pad, stage x_0
    for (int i = tid; i < 16 * LDS_K; i += 512)
        ((_Float16*)h_lds)[i] = (_Float16)0.0f;
    __syncthreads();
    if (tid < 256) {
        int m = tid >> 4, f = tid & 15;
        h_lds[m][Hsz + f] = (_Float16)x[((b0 + m) * Tsz + 0) * Fsz + f];
    }
    __syncthreads();

    // cell/publish/gather ownership: thread -> (m = tid>>5, slot = tid&31)
    const int cm = tid >> 5, cj = tid & 31;
    float c_st[2] = {0.f, 0.f};

    for (int t = 0; t < Tsz; ++t) {
        // ---- x_{t+1} prefetch: ISSUE FIRST (cold HBM miss hides under step)
        float xr = 0.0f;
        if (t + 1 < Tsz && tid < 256)
            xr = x[((b0 + (tid >> 4)) * Tsz + (t + 1)) * Fsz + (tid & 15)];

        // ---- A-frags from LDS; B-frags all from registers ----
        half8 afr[KTILES];
#pragma unroll
        for (int kt = 0; kt < KTILES; ++kt)
            afr[kt] = *(const half8*)&h_lds[n_in][kt * 32 + quad * 8];

        floatx4 acc[2] = {(floatx4){0.f,0.f,0.f,0.f}, (floatx4){0.f,0.f,0.f,0.f}};
#pragma unroll
        for (int gg = 0; gg < 2; ++gg) {
#pragma unroll
            for (int kt = 0; kt < KTILES; ++kt)
                acc[gg] = __builtin_amdgcn_mfma_f32_16x16x32_f16(afr[kt], wf[gg][kt], acc[gg], 0, 0, 0);
        }

        // ---- stage gate pre-activations to LDS ----
#pragma unroll
        for (int gg = 0; gg < 2; ++gg)
#pragma unroll
            for (int r = 0; r < 4; ++r)
                glds[gp * 2 + gg][quad * 4 + r][Jl * 16 + n_in] = acc[gg][r] + bs[gg];
        __syncthreads();   // G1: gates staged; afr reads done -> h_lds writable

        // ---- cell update: thread owns (cm, j_local = 2cj, 2cj+1) ----
        union { _Float16 f[2]; unsigned u; } pk;
#pragma unroll
        for (int e = 0; e < 2; ++e) {
            int jl = 2 * cj + e;
            float ig = glds[0][cm][jl];
            float fg = glds[1][cm][jl];
            float gg_ = glds[2][cm][jl];
            float og = glds[3][cm][jl];
            float si = 1.0f / (1.0f + __expf(-ig));
            float sf = 1.0f / (1.0f + __expf(-fg));
            float tg = 1.0f - 2.0f / (__expf(2.0f * gg_) + 1.0f);
            float so = 1.0f / (1.0f + __expf(-og));
            float c = sf * c_st[e] + si * tg;
            c_st[e] = c;
            float th = 1.0f - 2.0f / (__expf(2.0f * c) + 1.0f);
            pk.f[e] = (_Float16)(so * th);
        }

        const size_t rb = ((size_t)((bb * 2 + (t & 1)) * 16));   // ring base (rows)
        // publish FIRST (partner-visible chain), then local writes
        if (t + 1 < Tsz) {
            unsigned long long pv = ((unsigned long long)pk.u << 32) | (unsigned)(t + 1);
            __hip_atomic_store(&xbuf[(rb + cm) * 128 + ng * 32 + cj], pv,
                               __ATOMIC_RELAXED, __HIP_MEMORY_SCOPE_AGENT);
        }
        // own quarter of h_{t+1} straight into LDS (safe: reads done at G1)
        *(unsigned*)&h_lds[cm][ng * 64 + 2 * cj] = pk.u;
        // history write for k_mlp: NON-TEMPORAL -> no L2 allocate, xbuf survives
        __builtin_nontemporal_store(
            pk.u, &hh32[((size_t)(b0 + cm) * Tsz + t) * 128 + ng * 32 + cj]);

        if (t + 1 < Tsz) {
            // ---- gather 3 partner quarters: concurrent tagged-atom polls ----
            const unsigned want = (unsigned)(t + 1);
            unsigned long long* p1 = &xbuf[(rb + cm) * 128 + ((ng + 1) & 3) * 32 + cj];
            unsigned long long* p2 = &xbuf[(rb + cm) * 128 + ((ng + 2) & 3) * 32 + cj];
            unsigned long long* p3 = &xbuf[(rb + cm) * 128 + ((ng + 3) & 3) * 32 + cj];
            unsigned long long v1 = __hip_atomic_load(p1, __ATOMIC_RELAXED,
                                                      __HIP_MEMORY_SCOPE_AGENT);
            unsigned long long v2 = __hip_atomic_load(p2, __ATOMIC_RELAXED,
                                                      __HIP_MEMORY_SCOPE_AGENT);
            unsigned long long v3 = __hip_atomic_load(p3, __ATOMIC_RELAXED,
                                                      __HIP_MEMORY_SCOPE_AGENT);
            while ((unsigned)v1 != want || (unsigned)v2 != want || (unsigned)v3 != want) {
                v1 = __hip_atomic_load(p1, __ATOMIC_RELAXED, __HIP_MEMORY_SCOPE_AGENT);
                v2 = __hip_atomic_load(p2, __ATOMIC_RELAXED, __HIP_MEMORY_SCOPE_AGENT);
                v3 = __hip_atomic_load(p3, __ATOMIC_RELAXED, __HIP_MEMORY_SCOPE_AGENT);
            }
            *(unsigned*)&h_lds[cm][((ng + 1) & 3) * 64 + 2 * cj] = (unsigned)(v1 >> 32);
            *(unsigned*)&h_lds[cm][((ng + 2) & 3) * 64 + 2 * cj] = (unsigned)(v2 >> 32);
            *(unsigned*)&h_lds[cm][((ng + 3) & 3) * 64 + 2 * cj] = (unsigned)(v3 >> 32);
            if (tid < 256)
                h_lds[tid >> 4][Hsz + (tid & 15)] = (_Float16)xr;
            __syncthreads();   // G4: full h_{t+1} + x_{t+1} staged
        }
    }
}

// ---------------- MLP head v6: in-kernel weight swizzle + peeled pipeline --
// Grid is exactly 224 and 672 = 3*224, so every block does chunks
// {bid, bid+224, bid+448}. Fully peeled with two named buffers and both
// remaining loads issued up front -> NT HBM latency (~900cy) hides under
// fc1/fc2 compute. __launch_bounds__(512,2): don't let the allocator squeeze
// the 64 buffer VGPRs out (132KB LDS caps us at 1 WG/CU anyway).
__global__ __launch_bounds__(512, 2) void k_mlp6(
    const _Float16* __restrict__ hh, const float* __restrict__ fc1_w,
    const float* __restrict__ fc2_w, const float* __restrict__ b1,
    const float* __restrict__ b2, const float* __restrict__ w3,
    const float* __restrict__ b3, float* __restrict__ out) {
    __shared__ __align__(16) _Float16 w1sh[64 * 512];   // 64 KB
    __shared__ __align__(16) _Float16 w2sh[16 * 512];   // 16 KB
    __shared__ _Float16 st1[8][16][136];
    __shared__ _Float16 st2[8][16][72];

    const int tid = threadIdx.x;
    const int wave = tid >> 6, lane = tid & 63;
    const int n_in = lane & 15, quad = lane >> 4;

    {   // build fragment tables directly from fc1_w/fc2_w (was k_prep's job)
#pragma unroll
        for (int it = 0; it < 8; ++it) {
            int s = it * 512 + tid;            // s = tile*64 + ln
            int tile = s >> 6, ln = s & 63;
            int nt = tile >> 3, kt = tile & 7, ni = ln & 15, kg = ln >> 4;
            const float* src = &fc1_w[(nt * 16 + ni) * 256 + kt * 32 + kg * 8];
            half8 v;
#pragma unroll
            for (int e = 0; e < 8; ++e) v[e] = (_Float16)src[e];
            ((half8*)w1sh)[s] = v;
        }
#pragma unroll
        for (int it = 0; it < 2; ++it) {
            int s = it * 512 + tid;
            int tile = s >> 6, ln = s & 63;
            int nt = tile >> 2, kt = tile & 3, ni = ln & 15, kg = ln >> 4;
            const float* src = &fc2_w[(nt * 16 + ni) * 128 + kt * 32 + kg * 8];
            half8 v;
#pragma unroll
            for (int e = 0; e < 8; ++e) v[e] = (_Float16)src[e];
            ((half8*)w2sh)[s] = v;
        }
    }
    __syncthreads();

    uint4v bufA[8], bufB[8], bufC[8];
    const int ch0 = blockIdx.x, ch1 = blockIdx.x + 224, ch2 = blockIdx.x + 448;

#define MLP_LOAD(dst, ch)                                                      \
    {                                                                          \
        const int tok0_ = (ch) * 128 + wave * 16;                              \
        _Pragma("unroll")                                                      \
        for (int kt = 0; kt < 8; ++kt)                                         \
            dst[kt] = __builtin_nontemporal_load(                              \
                (const uint4v*)&hh[(size_t)(tok0_ + n_in) * 256 + kt * 32 +    \
                                   quad * 8]);                                 \
    }

    MLP_LOAD(bufA, ch0)
    MLP_LOAD(bufB, ch1)
    MLP_LOAD(bufC, ch2)

    auto compute = [&](const uint4v* raw, int chunk) {
        const int tok0 = chunk * 128 + wave * 16;
        half8 afr[8];
#pragma unroll
        for (int kt = 0; kt < 8; ++kt)
            afr[kt] = __builtin_bit_cast(half8, raw[kt]);

#pragma unroll
        for (int nt = 0; nt < 8; ++nt) {
            floatx4 a = (floatx4){0.f, 0.f, 0.f, 0.f};
#pragma unroll
            for (int kt = 0; kt < 8; ++kt) {
                half8 bfr = *(const half8*)&w1sh[(nt * 8 + kt) * 512 + lane * 8];
                a = __builtin_amdgcn_mfma_f32_16x16x32_f16(afr[kt], bfr, a, 0, 0, 0);
            }
            float bbv = b1[nt * 16 + n_in];
#pragma unroll
            for (int r = 0; r < 4; ++r) {
                float v = a[r] + bbv;
                st1[wave][quad * 4 + r][nt * 16 + n_in] = (_Float16)(v > 0.f ? v : 0.f);
            }
        }

        half8 a2[4];
#pragma unroll
        for (int kt = 0; kt < 4; ++kt)
            a2[kt] = *(const half8*)&st1[wave][n_in][kt * 32 + quad * 8];
#pragma unroll
        for (int nt = 0; nt < 4; ++nt) {
            floatx4 a = (floatx4){0.f, 0.f, 0.f, 0.f};
#pragma unroll
            for (int kt = 0; kt < 4; ++kt) {
                half8 bfr = *(const half8*)&w2sh[(nt * 4 + kt) * 512 + lane * 8];
                a = __builtin_amdgcn_mfma_f32_16x16x32_f16(a2[kt], bfr, a, 0, 0, 0);
            }
            float bbv = b2[nt * 16 + n_in];
#pragma unroll
            for (int r = 0; r < 4; ++r) {
                float v = a[r] + bbv;
                st2[wave][quad * 4 + r][nt * 16 + n_in] = (_Float16)(v > 0.f ? v : 0.f);
            }
        }

        float p = 0.0f;
#pragma unroll
        for (int e = 0; e < 16; ++e)
            p += (float)st2[wave][n_in][quad * 16 + e] * w3[quad * 16 + e];
        p += __shfl_down(p, 32);
        p += __shfl_down(p, 16);
        if (quad == 0) out[tok0 + n_in] = p + b3[0];
    };

    compute(bufA, ch0);
    compute(bufB, ch1);
    compute(bufC, ch2);
#undef MLP_LOAD
}

extern "C" void kernel_launch(void* const* d_in, const int* in_sizes, int n_in,
                              void* d_out, int out_size, void* d_ws, size_t ws_size,
                              hipStream_t stream) {
    const float* x     = (const float*)d_in[0];
    const float* w_ih  = (const float*)d_in[1];
    const float* w_hh  = (const float*)d_in[2];
    const float* b_ih  = (const float*)d_in[3];
    const float* b_hh  = (const float*)d_in[4];
    const float* fc1_w = (const float*)d_in[5];
    const float* fc1_b = (const float*)d_in[6];
    const float* fc2_w = (const float*)d_in[7];
    const float* fc2_b = (const float*)d_in[8];
    const float* fc3_w = (const float*)d_in[9];
    const float* fc3_b = (const float*)d_in[10];

    char* ws = (char*)d_ws;
    _Float16* hhist= (_Float16*)(ws + HH_OFF);
    unsigned long long* xbuf = (unsigned long long*)(ws + XBUF_OFF);

    k_lstm15<<<128, 512, 0, stream>>>(x, w_ih, w_hh, b_ih, b_hh,
                                      (unsigned*)hhist, xbuf);
    k_mlp6<<<224, 512, 0, stream>>>(hhist, fc1_w, fc2_w, fc1_b, fc2_b,
                                    fc3_w, fc3_b, (float*)d_out);
}

// Round 4
// 489.128 us; speedup vs baseline: 1.0069x; 1.0069x over previous
//
#include <hip/hip_runtime.h>

typedef _Float16 half8 __attribute__((ext_vector_type(8)));
typedef float floatx4 __attribute__((ext_vector_type(4)));
typedef unsigned uint4v __attribute__((ext_vector_type(4)));

#define Bsz 512
#define Tsz 168
#define Fsz 16
#define Hsz 256
#define KTILES 9      // K = 288 = 9 * 32  (256 h + 16 x + 16 zero pad)
#define LDS_K 296     // padded LDS row stride in halves

// workspace layout (bytes, all 16B aligned)
#define WSW_OFF   0          // swizzled [w_hh|w_ih|0] f16 frags: 64nt*9kt*64lane*16B = 589824
#define BIAS_OFF  589824     // reordered (b_ih+b_hh) fp32: 1024*4 = 4096
#define HH_OFF    675840     // h history f16 [B][T][H]: 512*168*256*2 = 44040192
#define XBUF_OFF  (HH_OFF + 44040192)   // tagged exchange ring: 32bb*2*16m*128slot*8B = 1 MB

// ---------------- prep: lstm weight swizzle + bias (f16 frag table) --------
// The lstm kernel loads its frags as pre-swizzled f16 (1 dwordx4/frag).
// v15's float+cvt prologue got sunk into the t-loop by LLVM's remat and cost
// ~70us. 148 blocks: 144 wsw + 4 bias.
__global__ __launch_bounds__(256) void k_prep(
    const float* __restrict__ w_hh, const float* __restrict__ w_ih,
    const float* __restrict__ b_ih, const float* __restrict__ b_hh,
    _Float16* __restrict__ wsw, float* __restrict__ bias) {
    const int b = blockIdx.x, tid = threadIdx.x;
    const int lane = tid & 63, sub = tid >> 6;
    if (b < 144) {                         // w_hh|w_ih swizzle: 576 tiles
        int tile = b * 4 + sub;            // nt*9 + kt
        int nt = tile / KTILES, kt = tile - nt * KTILES;
        int n_in = lane & 15, kg = lane >> 4;
        int J = nt >> 2, g = nt & 3;
        int n_orig = g * 256 + J * 16 + n_in;
        half8 v;
#pragma unroll
        for (int e = 0; e < 8; ++e) {
            int k = kt * 32 + kg * 8 + e;
            float f;
            if (k < 256)      f = w_hh[n_orig * 256 + k];
            else if (k < 272) f = w_ih[n_orig * 16 + (k - 256)];
            else              f = 0.0f;
            v[e] = (_Float16)f;
        }
        ((half8*)wsw)[tile * 64 + lane] = v;
    } else {                               // bias reorder: 1024
        int id = (b - 144) * 256 + tid;
        int nt = id >> 4, n = id & 15;
        int J = nt >> 2, g = nt & 3;
        int n_orig = g * 256 + J * 16 + n;
        bias[id] = b_ih[n_orig] + b_hh[n_orig];
    }
}

// ---------------- recurrent LSTM v16: REGISTER weights, PINNED -------------
// R15 post-mortem: launch_bounds alone can't force residency — LLVM remats
// loop-invariant const loads by SINKING them into the t-loop (VGPR=80 both
// rounds). v16 loads the 18 f16 frags from wsw in the prologue and pins each
// with asm volatile("" : "+v"(frag)): the value is now opaque (not "a load
// result"), so reload-remat is illegal and the allocator must keep all 72
// VGPRs live. Step body then has ZERO global weight traffic.
// Kept from v15: x-prefetch at top (hides ~900cy cold miss under full step),
// publish-first, unconditional 3-load poll retry.
// (R3 was an infra failure — container died twice, no counters; resubmit.)
__global__ __launch_bounds__(512, 2) void k_lstm16(
    const float* __restrict__ x, const _Float16* __restrict__ wsw,
    const float* __restrict__ bias, unsigned* __restrict__ hh32,
    unsigned long long* __restrict__ xbuf) {
    __shared__ __align__(16) _Float16 h_lds[16][LDS_K];   // h | x | pad
    __shared__ float glds[4][16][68];                     // [gate][m][j_local], pad 68

    const int tid = threadIdx.x;
    const int wave = tid >> 6, lane = tid & 63;
    const int n_in = lane & 15, quad = lane >> 4;
    const int bb = blockIdx.x & 31, ng = blockIdx.x >> 5;   // XCD-colocated swizzle
    const int b0 = bb * 16;
    const int Jl = wave & 3;               // local J-block 0..3
    const int gp = wave >> 2;              // gate pair: 0 -> (i,f), 1 -> (g,o)

    // ---- prologue: 18 weight B-frags + bias into VGPRs, then PIN ----
    float bs[2];
    uint4v wf[2][KTILES];
#pragma unroll
    for (int gg = 0; gg < 2; ++gg) {
        const int nt = ng * 16 + Jl * 4 + gp * 2 + gg;
        bs[gg] = bias[nt * 16 + n_in];
#pragma unroll
        for (int kt = 0; kt < KTILES; ++kt)
            wf[gg][kt] = ((const uint4v*)wsw)[((size_t)nt * KTILES + kt) * 64 + lane];
    }
#pragma unroll
    for (int gg = 0; gg < 2; ++gg) {
        asm volatile("" : "+v"(bs[gg]));
#pragma unroll
        for (int kt = 0; kt < KTILES; ++kt)
            asm volatile("" : "+v"(wf[gg][kt]));
    }

    // zero h0 + x + pad, stage x_0
    for (int i = tid; i < 16 * LDS_K; i += 512)
        ((_Float16*)h_lds)[i] = (_Float16)0.0f;
    __syncthreads();
    if (tid < 256) {
        int m = tid >> 4, f = tid & 15;
        h_lds[m][Hsz + f] = (_Float16)x[((b0 + m) * Tsz + 0) * Fsz + f];
    }
    __syncthreads();

    // cell/publish/gather ownership: thread -> (m = tid>>5, slot = tid&31)
    const int cm = tid >> 5, cj = tid & 31;
    float c_st[2] = {0.f, 0.f};

    for (int t = 0; t < Tsz; ++t) {
        // ---- x_{t+1} prefetch: ISSUE FIRST (cold HBM miss hides under step)
        float xr = 0.0f;
        if (t + 1 < Tsz && tid < 256)
            xr = x[((b0 + (tid >> 4)) * Tsz + (t + 1)) * Fsz + (tid & 15)];

        // ---- A-frags from LDS; B-frags all from pinned registers ----
        half8 afr[KTILES];
#pragma unroll
        for (int kt = 0; kt < KTILES; ++kt)
            afr[kt] = *(const half8*)&h_lds[n_in][kt * 32 + quad * 8];

        floatx4 acc[2] = {(floatx4){0.f,0.f,0.f,0.f}, (floatx4){0.f,0.f,0.f,0.f}};
#pragma unroll
        for (int gg = 0; gg < 2; ++gg) {
#pragma unroll
            for (int kt = 0; kt < KTILES; ++kt)
                acc[gg] = __builtin_amdgcn_mfma_f32_16x16x32_f16(
                    afr[kt], __builtin_bit_cast(half8, wf[gg][kt]), acc[gg], 0, 0, 0);
        }

        // ---- stage gate pre-activations to LDS ----
#pragma unroll
        for (int gg = 0; gg < 2; ++gg)
#pragma unroll
            for (int r = 0; r < 4; ++r)
                glds[gp * 2 + gg][quad * 4 + r][Jl * 16 + n_in] = acc[gg][r] + bs[gg];
        __syncthreads();   // G1: gates staged; afr reads done -> h_lds writable

        // ---- cell update: thread owns (cm, j_local = 2cj, 2cj+1) ----
        union { _Float16 f[2]; unsigned u; } pk;
#pragma unroll
        for (int e = 0; e < 2; ++e) {
            int jl = 2 * cj + e;
            float ig = glds[0][cm][jl];
            float fg = glds[1][cm][jl];
            float gg_ = glds[2][cm][jl];
            float og = glds[3][cm][jl];
            float si = 1.0f / (1.0f + __expf(-ig));
            float sf = 1.0f / (1.0f + __expf(-fg));
            float tg = 1.0f - 2.0f / (__expf(2.0f * gg_) + 1.0f);
            float so = 1.0f / (1.0f + __expf(-og));
            float c = sf * c_st[e] + si * tg;
            c_st[e] = c;
            float th = 1.0f - 2.0f / (__expf(2.0f * c) + 1.0f);
            pk.f[e] = (_Float16)(so * th);
        }

        const size_t rb = ((size_t)((bb * 2 + (t & 1)) * 16));   // ring base (rows)
        // publish FIRST (partner-visible chain), then local writes
        if (t + 1 < Tsz) {
            unsigned long long pv = ((unsigned long long)pk.u << 32) | (unsigned)(t + 1);
            __hip_atomic_store(&xbuf[(rb + cm) * 128 + ng * 32 + cj], pv,
                               __ATOMIC_RELAXED, __HIP_MEMORY_SCOPE_AGENT);
        }
        // own quarter of h_{t+1} straight into LDS (safe: reads done at G1)
        *(unsigned*)&h_lds[cm][ng * 64 + 2 * cj] = pk.u;
        // history write for k_mlp: NON-TEMPORAL -> no L2 allocate, xbuf survives
        __builtin_nontemporal_store(
            pk.u, &hh32[((size_t)(b0 + cm) * Tsz + t) * 128 + ng * 32 + cj]);

        if (t + 1 < Tsz) {
            // ---- gather 3 partner quarters: concurrent tagged-atom polls ----
            const unsigned want = (unsigned)(t + 1);
            unsigned long long* p1 = &xbuf[(rb + cm) * 128 + ((ng + 1) & 3) * 32 + cj];
            unsigned long long* p2 = &xbuf[(rb + cm) * 128 + ((ng + 2) & 3) * 32 + cj];
            unsigned long long* p3 = &xbuf[(rb + cm) * 128 + ((ng + 3) & 3) * 32 + cj];
            unsigned long long v1 = __hip_atomic_load(p1, __ATOMIC_RELAXED,
                                                      __HIP_MEMORY_SCOPE_AGENT);
            unsigned long long v2 = __hip_atomic_load(p2, __ATOMIC_RELAXED,
                                                      __HIP_MEMORY_SCOPE_AGENT);
            unsigned long long v3 = __hip_atomic_load(p3, __ATOMIC_RELAXED,
                                                      __HIP_MEMORY_SCOPE_AGENT);
            while ((unsigned)v1 != want || (unsigned)v2 != want || (unsigned)v3 != want) {
                v1 = __hip_atomic_load(p1, __ATOMIC_RELAXED, __HIP_MEMORY_SCOPE_AGENT);
                v2 = __hip_atomic_load(p2, __ATOMIC_RELAXED, __HIP_MEMORY_SCOPE_AGENT);
                v3 = __hip_atomic_load(p3, __ATOMIC_RELAXED, __HIP_MEMORY_SCOPE_AGENT);
            }
            *(unsigned*)&h_lds[cm][((ng + 1) & 3) * 64 + 2 * cj] = (unsigned)(v1 >> 32);
            *(unsigned*)&h_lds[cm][((ng + 2) & 3) * 64 + 2 * cj] = (unsigned)(v2 >> 32);
            *(unsigned*)&h_lds[cm][((ng + 3) & 3) * 64 + 2 * cj] = (unsigned)(v3 >> 32);
            if (tid < 256)
                h_lds[tid >> 4][Hsz + (tid & 15)] = (_Float16)xr;
            __syncthreads();   // G4: full h_{t+1} + x_{t+1} staged
        }
    }
}

// ---------------- MLP head v6: in-kernel weight swizzle + peeled pipeline --
// (unchanged — residue is ~77us, not the current priority)
__global__ __launch_bounds__(512, 2) void k_mlp6(
    const _Float16* __restrict__ hh, const float* __restrict__ fc1_w,
    const float* __restrict__ fc2_w, const float* __restrict__ b1,
    const float* __restrict__ b2, const float* __restrict__ w3,
    const float* __restrict__ b3, float* __restrict__ out) {
    __shared__ __align__(16) _Float16 w1sh[64 * 512];   // 64 KB
    __shared__ __align__(16) _Float16 w2sh[16 * 512];   // 16 KB
    __shared__ _Float16 st1[8][16][136];
    __shared__ _Float16 st2[8][16][72];

    const int tid = threadIdx.x;
    const int wave = tid >> 6, lane = tid & 63;
    const int n_in = lane & 15, quad = lane >> 4;

    {   // build fragment tables directly from fc1_w/fc2_w
#pragma unroll
        for (int it = 0; it < 8; ++it) {
            int s = it * 512 + tid;            // s = tile*64 + ln
            int tile = s >> 6, ln = s & 63;
            int nt = tile >> 3, kt = tile & 7, ni = ln & 15, kg = ln >> 4;
            const float* src = &fc1_w[(nt * 16 + ni) * 256 + kt * 32 + kg * 8];
            half8 v;
#pragma unroll
            for (int e = 0; e < 8; ++e) v[e] = (_Float16)src[e];
            ((half8*)w1sh)[s] = v;
        }
#pragma unroll
        for (int it = 0; it < 2; ++it) {
            int s = it * 512 + tid;
            int tile = s >> 6, ln = s & 63;
            int nt = tile >> 2, kt = tile & 3, ni = ln & 15, kg = ln >> 4;
            const float* src = &fc2_w[(nt * 16 + ni) * 128 + kt * 32 + kg * 8];
            half8 v;
#pragma unroll
            for (int e = 0; e < 8; ++e) v[e] = (_Float16)src[e];
            ((half8*)w2sh)[s] = v;
        }
    }
    __syncthreads();

    uint4v bufA[8], bufB[8], bufC[8];
    const int ch0 = blockIdx.x, ch1 = blockIdx.x + 224, ch2 = blockIdx.x + 448;

#define MLP_LOAD(dst, ch)                                                      \
    {                                                                          \
        const int tok0_ = (ch) * 128 + wave * 16;                              \
        _Pragma("unroll")                                                      \
        for (int kt = 0; kt < 8; ++kt)                                         \
            dst[kt] = __builtin_nontemporal_load(                              \
                (const uint4v*)&hh[(size_t)(tok0_ + n_in) * 256 + kt * 32 +    \
                                   quad * 8]);                                 \
    }

    MLP_LOAD(bufA, ch0)
    MLP_LOAD(bufB, ch1)
    MLP_LOAD(bufC, ch2)

    auto compute = [&](const uint4v* raw, int chunk) {
        const int tok0 = chunk * 128 + wave * 16;
        half8 afr[8];
#pragma unroll
        for (int kt = 0; kt < 8; ++kt)
            afr[kt] = __builtin_bit_cast(half8, raw[kt]);

#pragma unroll
        for (int nt = 0; nt < 8; ++nt) {
            floatx4 a = (floatx4){0.f, 0.f, 0.f, 0.f};
#pragma unroll
            for (int kt = 0; kt < 8; ++kt) {
                half8 bfr = *(const half8*)&w1sh[(nt * 8 + kt) * 512 + lane * 8];
                a = __builtin_amdgcn_mfma_f32_16x16x32_f16(afr[kt], bfr, a, 0, 0, 0);
            }
            float bbv = b1[nt * 16 + n_in];
#pragma unroll
            for (int r = 0; r < 4; ++r) {
                float v = a[r] + bbv;
                st1[wave][quad * 4 + r][nt * 16 + n_in] = (_Float16)(v > 0.f ? v : 0.f);
            }
        }

        half8 a2[4];
#pragma unroll
        for (int kt = 0; kt < 4; ++kt)
            a2[kt] = *(const half8*)&st1[wave][n_in][kt * 32 + quad * 8];
#pragma unroll
        for (int nt = 0; nt < 4; ++nt) {
            floatx4 a = (floatx4){0.f, 0.f, 0.f, 0.f};
#pragma unroll
            for (int kt = 0; kt < 4; ++kt) {
                half8 bfr = *(const half8*)&w2sh[(nt * 4 + kt) * 512 + lane * 8];
                a = __builtin_amdgcn_mfma_f32_16x16x32_f16(a2[kt], bfr, a, 0, 0, 0);
            }
            float bbv = b2[nt * 16 + n_in];
#pragma unroll
            for (int r = 0; r < 4; ++r) {
                float v = a[r] + bbv;
                st2[wave][quad * 4 + r][nt * 16 + n_in] = (_Float16)(v > 0.f ? v : 0.f);
            }
        }

        float p = 0.0f;
#pragma unroll
        for (int e = 0; e < 16; ++e)
            p += (float)st2[wave][n_in][quad * 16 + e] * w3[quad * 16 + e];
        p += __shfl_down(p, 32);
        p += __shfl_down(p, 16);
        if (quad == 0) out[tok0 + n_in] = p + b3[0];
    };

    compute(bufA, ch0);
    compute(bufB, ch1);
    compute(bufC, ch2);
#undef MLP_LOAD
}

extern "C" void kernel_launch(void* const* d_in, const int* in_sizes, int n_in,
                              void* d_out, int out_size, void* d_ws, size_t ws_size,
                              hipStream_t stream) {
    const float* x     = (const float*)d_in[0];
    const float* w_ih  = (const float*)d_in[1];
    const float* w_hh  = (const float*)d_in[2];
    const float* b_ih  = (const float*)d_in[3];
    const float* b_hh  = (const float*)d_in[4];
    const float* fc1_w = (const float*)d_in[5];
    const float* fc1_b = (const float*)d_in[6];
    const float* fc2_w = (const float*)d_in[7];
    const float* fc2_b = (const float*)d_in[8];
    const float* fc3_w = (const float*)d_in[9];
    const float* fc3_b = (const float*)d_in[10];

    char* ws = (char*)d_ws;
    _Float16* wsw  = (_Float16*)(ws + WSW_OFF);
    float*    bias = (float*)(ws + BIAS_OFF);
    _Float16* hhist= (_Float16*)(ws + HH_OFF);
    unsigned long long* xbuf = (unsigned long long*)(ws + XBUF_OFF);

    k_prep<<<148, 256, 0, stream>>>(w_hh, w_ih, b_ih, b_hh, wsw, bias);
    k_lstm16<<<128, 512, 0, stream>>>(x, wsw, bias, (unsigned*)hhist, xbuf);
    k_mlp6<<<224, 512, 0, stream>>>(hhist, fc1_w, fc2_w, fc1_b, fc2_b,
                                    fc3_w, fc3_b, (float*)d_out);
}

// Round 5
// 458.556 us; speedup vs baseline: 1.0740x; 1.0667x over previous
//
#include <hip/hip_runtime.h>

typedef _Float16 half8 __attribute__((ext_vector_type(8)));
typedef float floatx4 __attribute__((ext_vector_type(4)));
typedef unsigned uint4v __attribute__((ext_vector_type(4)));

#define Bsz 512
#define Tsz 168
#define Fsz 16
#define Hsz 256
#define KTILES 9      // K = 288 = 9 * 32  (256 h + 16 x + 16 zero pad)
#define LDS_K 296     // padded LDS row stride in halves

// workspace layout (bytes, all 16B aligned)
#define WSW_OFF   0          // swizzled [w_hh|w_ih|0] f16 frags: 64nt*9kt*64lane*16B = 589824
#define BIAS_OFF  589824     // reordered (b_ih+b_hh) fp32: 1024*4 = 4096
#define HH_OFF    675840     // h history f16 [B][T][H]: 512*168*256*2 = 44040192
#define XBUF_OFF  (HH_OFF + 44040192)   // tagged ring: 32bb*2*16m*256slot*8B = 2 MB

// ---------------- prep: lstm weight swizzle + bias (f16 frag table) --------
// Unchanged table; v17's 8-way WGs index the same 64nt x 9kt tiles.
__global__ __launch_bounds__(256) void k_prep(
    const float* __restrict__ w_hh, const float* __restrict__ w_ih,
    const float* __restrict__ b_ih, const float* __restrict__ b_hh,
    _Float16* __restrict__ wsw, float* __restrict__ bias) {
    const int b = blockIdx.x, tid = threadIdx.x;
    const int lane = tid & 63, sub = tid >> 6;
    if (b < 144) {                         // w_hh|w_ih swizzle: 576 tiles
        int tile = b * 4 + sub;            // nt*9 + kt
        int nt = tile / KTILES, kt = tile - nt * KTILES;
        int n_in = lane & 15, kg = lane >> 4;
        int J = nt >> 2, g = nt & 3;
        int n_orig = g * 256 + J * 16 + n_in;
        half8 v;
#pragma unroll
        for (int e = 0; e < 8; ++e) {
            int k = kt * 32 + kg * 8 + e;
            float f;
            if (k < 256)      f = w_hh[n_orig * 256 + k];
            else if (k < 272) f = w_ih[n_orig * 16 + (k - 256)];
            else              f = 0.0f;
            v[e] = (_Float16)f;
        }
        ((half8*)wsw)[tile * 64 + lane] = v;
    } else {                               // bias reorder: 1024
        int id = (b - 144) * 256 + tid;
        int nt = id >> 4, n = id & 15;
        int J = nt >> 2, g = nt & 3;
        int n_orig = g * 256 + J * 16 + n;
        bias[id] = b_ih[n_orig] + b_hh[n_orig];
    }
}

// ---------------- recurrent LSTM v17: 8-way gate split, 256 WGs ------------
// R16 post-mortem: three rounds of register-pinning all lost to the
// allocator (VGPR stuck at 72; pin satisfied by scratch spill). v17 keeps
// v14's proven body (342us: sunk L2 weight reloads, launch_bounds(512,1),
// v14 ordering) and instead halves the per-wave serial chain structurally:
// H split 8 ways (was 4) -> grid 256 (all CUs), 1 nt/wave (9 MFMAs, was 18),
// 9 frag reloads (was 18), 1 cell element/thread (4 exps, was 8).
// Exchange generalizes: publish 1 f16/thread as tagged 8B atom, poll 7
// partners (XCD-colocated: (bb+32k)%8 == bb%8).
__global__ __launch_bounds__(512, 1) void k_lstm17(
    const float* __restrict__ x, const _Float16* __restrict__ wsw,
    const float* __restrict__ bias, unsigned* __restrict__ hh32,
    unsigned long long* __restrict__ xbuf) {
    __shared__ __align__(16) _Float16 h_lds[16][LDS_K];   // h | x | pad
    __shared__ float glds[4][16][36];                     // [gate][m][col], pad 36

    const int tid = threadIdx.x;
    const int wave = tid >> 6, lane = tid & 63;
    const int n_in = lane & 15, quad = lane >> 4;
    const int bb = blockIdx.x & 31, ng = blockIdx.x >> 5;   // ng in [0,8)
    const int b0 = bb * 16;
    const int Jl = wave & 1;               // local col-tile 0..1
    const int g  = wave >> 1;              // gate 0..3 (i,f,g,o)
    const int nt = (ng * 2 + Jl) * 4 + g;  // global tile in the 64-nt table

    // ---- per-wave weight frags + bias (compiler will sink reloads to L2;
    //      that is v14's measured-fast behavior, now at half volume) ----
    const float bs = bias[nt * 16 + n_in];
    half8 wf[KTILES];
#pragma unroll
    for (int kt = 0; kt < KTILES; ++kt)
        wf[kt] = ((const half8*)wsw)[((size_t)nt * KTILES + kt) * 64 + lane];

    // zero h0 + x + pad, stage x_0
    for (int i = tid; i < 16 * LDS_K; i += 512)
        ((_Float16*)h_lds)[i] = (_Float16)0.0f;
    __syncthreads();
    if (tid < 256) {
        int m = tid >> 4, f = tid & 15;
        h_lds[m][Hsz + f] = (_Float16)x[((b0 + m) * Tsz + 0) * Fsz + f];
    }
    __syncthreads();

    // cell/publish/gather ownership: thread -> (m = tid>>5, col = tid&31)
    const int cm = tid >> 5, cj = tid & 31;
    float c_st = 0.f;
    unsigned short* hh16 = (unsigned short*)hh32;

    for (int t = 0; t < Tsz; ++t) {
        // ---- A-frags from LDS; B-frags from (sunk) regs ----
        half8 afr[KTILES];
#pragma unroll
        for (int kt = 0; kt < KTILES; ++kt)
            afr[kt] = *(const half8*)&h_lds[n_in][kt * 32 + quad * 8];

        floatx4 acc = (floatx4){0.f, 0.f, 0.f, 0.f};
#pragma unroll
        for (int kt = 0; kt < KTILES; ++kt)
            acc = __builtin_amdgcn_mfma_f32_16x16x32_f16(afr[kt], wf[kt], acc, 0, 0, 0);

        // ---- stage gate pre-activations to LDS ----
#pragma unroll
        for (int r = 0; r < 4; ++r)
            glds[g][quad * 4 + r][Jl * 16 + n_in] = acc[r] + bs;
        __syncthreads();   // G1: gates staged; afr reads done -> h_lds writable

        // ---- cell update: thread owns (cm, col cj) ----
        float ig = glds[0][cm][cj];
        float fg = glds[1][cm][cj];
        float gv = glds[2][cm][cj];
        float og = glds[3][cm][cj];
        float si = 1.0f / (1.0f + __expf(-ig));
        float sf = 1.0f / (1.0f + __expf(-fg));
        float tg = 1.0f - 2.0f / (__expf(2.0f * gv) + 1.0f);
        float so = 1.0f / (1.0f + __expf(-og));
        float c = sf * c_st + si * tg;
        c_st = c;
        float th = 1.0f - 2.0f / (__expf(2.0f * c) + 1.0f);
        _Float16 hval = (_Float16)(so * th);
        unsigned short hu = __builtin_bit_cast(unsigned short, hval);

        // own slice of h_{t+1} straight into LDS (safe: reads done at G1)
        h_lds[cm][ng * 32 + cj] = hval;

        const size_t rb = ((size_t)((bb * 2 + (t & 1)) * 16));   // ring base (rows)
        if (t + 1 < Tsz) {
            // publish own slot as a single tagged atom {data | t+1} (L2-resident)
            unsigned long long pv =
                ((unsigned long long)hu << 32) | (unsigned)(t + 1);
            __hip_atomic_store(&xbuf[(rb + cm) * 256 + ng * 32 + cj], pv,
                               __ATOMIC_RELAXED, __HIP_MEMORY_SCOPE_AGENT);
        }
        // history write for k_mlp: NON-TEMPORAL -> no L2 allocate, xbuf survives
        __builtin_nontemporal_store(
            hu, &hh16[((size_t)(b0 + cm) * Tsz + t) * 256 + ng * 32 + cj]);

        if (t + 1 < Tsz) {
            // prefetch x_{t+1}; ack overlaps the polls below
            float xr = 0.0f;
            if (tid < 256)
                xr = x[((b0 + (tid >> 4)) * Tsz + (t + 1)) * Fsz + (tid & 15)];

            // ---- gather 7 partner slices: concurrent tagged-atom polls ----
            const unsigned want = (unsigned)(t + 1);
            unsigned long long* pp[7];
            unsigned long long vv[7];
#pragma unroll
            for (int k = 0; k < 7; ++k)
                pp[k] = &xbuf[(rb + cm) * 256 + ((ng + k + 1) & 7) * 32 + cj];
#pragma unroll
            for (int k = 0; k < 7; ++k)
                vv[k] = __hip_atomic_load(pp[k], __ATOMIC_RELAXED,
                                          __HIP_MEMORY_SCOPE_AGENT);
            while (true) {
                bool ok = true;
#pragma unroll
                for (int k = 0; k < 7; ++k) ok &= ((unsigned)vv[k] == want);
                if (ok) break;
#pragma unroll
                for (int k = 0; k < 7; ++k)
                    if ((unsigned)vv[k] != want)
                        vv[k] = __hip_atomic_load(pp[k], __ATOMIC_RELAXED,
                                                  __HIP_MEMORY_SCOPE_AGENT);
            }
#pragma unroll
            for (int k = 0; k < 7; ++k)
                h_lds[cm][((ng + k + 1) & 7) * 32 + cj] = __builtin_bit_cast(
                    _Float16, (unsigned short)(vv[k] >> 32));
            if (tid < 256)
                h_lds[tid >> 4][Hsz + (tid & 15)] = (_Float16)xr;
            __syncthreads();   // G4: full h_{t+1} + x_{t+1} staged
        }
    }
}

// ---------------- MLP head v6: in-kernel weight swizzle + peeled pipeline --
// (unchanged — residue is ~75-80us across mlp4/5/6; not the current lever)
__global__ __launch_bounds__(512, 2) void k_mlp6(
    const _Float16* __restrict__ hh, const float* __restrict__ fc1_w,
    const float* __restrict__ fc2_w, const float* __restrict__ b1,
    const float* __restrict__ b2, const float* __restrict__ w3,
    const float* __restrict__ b3, float* __restrict__ out) {
    __shared__ __align__(16) _Float16 w1sh[64 * 512];   // 64 KB
    __shared__ __align__(16) _Float16 w2sh[16 * 512];   // 16 KB
    __shared__ _Float16 st1[8][16][136];
    __shared__ _Float16 st2[8][16][72];

    const int tid = threadIdx.x;
    const int wave = tid >> 6, lane = tid & 63;
    const int n_in = lane & 15, quad = lane >> 4;

    {   // build fragment tables directly from fc1_w/fc2_w
#pragma unroll
        for (int it = 0; it < 8; ++it) {
            int s = it * 512 + tid;            // s = tile*64 + ln
            int tile = s >> 6, ln = s & 63;
            int nt = tile >> 3, kt = tile & 7, ni = ln & 15, kg = ln >> 4;
            const float* src = &fc1_w[(nt * 16 + ni) * 256 + kt * 32 + kg * 8];
            half8 v;
#pragma unroll
            for (int e = 0; e < 8; ++e) v[e] = (_Float16)src[e];
            ((half8*)w1sh)[s] = v;
        }
#pragma unroll
        for (int it = 0; it < 2; ++it) {
            int s = it * 512 + tid;
            int tile = s >> 6, ln = s & 63;
            int nt = tile >> 2, kt = tile & 3, ni = ln & 15, kg = ln >> 4;
            const float* src = &fc2_w[(nt * 16 + ni) * 128 + kt * 32 + kg * 8];
            half8 v;
#pragma unroll
            for (int e = 0; e < 8; ++e) v[e] = (_Float16)src[e];
            ((half8*)w2sh)[s] = v;
        }
    }
    __syncthreads();

    uint4v bufA[8], bufB[8], bufC[8];
    const int ch0 = blockIdx.x, ch1 = blockIdx.x + 224, ch2 = blockIdx.x + 448;

#define MLP_LOAD(dst, ch)                                                      \
    {                                                                          \
        const int tok0_ = (ch) * 128 + wave * 16;                              \
        _Pragma("unroll")                                                      \
        for (int kt = 0; kt < 8; ++kt)                                         \
            dst[kt] = __builtin_nontemporal_load(                              \
                (const uint4v*)&hh[(size_t)(tok0_ + n_in) * 256 + kt * 32 +    \
                                   quad * 8]);                                 \
    }

    MLP_LOAD(bufA, ch0)
    MLP_LOAD(bufB, ch1)
    MLP_LOAD(bufC, ch2)

    auto compute = [&](const uint4v* raw, int chunk) {
        const int tok0 = chunk * 128 + wave * 16;
        half8 afr[8];
#pragma unroll
        for (int kt = 0; kt < 8; ++kt)
            afr[kt] = __builtin_bit_cast(half8, raw[kt]);

#pragma unroll
        for (int nt = 0; nt < 8; ++nt) {
            floatx4 a = (floatx4){0.f, 0.f, 0.f, 0.f};
#pragma unroll
            for (int kt = 0; kt < 8; ++kt) {
                half8 bfr = *(const half8*)&w1sh[(nt * 8 + kt) * 512 + lane * 8];
                a = __builtin_amdgcn_mfma_f32_16x16x32_f16(afr[kt], bfr, a, 0, 0, 0);
            }
            float bbv = b1[nt * 16 + n_in];
#pragma unroll
            for (int r = 0; r < 4; ++r) {
                float v = a[r] + bbv;
                st1[wave][quad * 4 + r][nt * 16 + n_in] = (_Float16)(v > 0.f ? v : 0.f);
            }
        }

        half8 a2[4];
#pragma unroll
        for (int kt = 0; kt < 4; ++kt)
            a2[kt] = *(const half8*)&st1[wave][n_in][kt * 32 + quad * 8];
#pragma unroll
        for (int nt = 0; nt < 4; ++nt) {
            floatx4 a = (floatx4){0.f, 0.f, 0.f, 0.f};
#pragma unroll
            for (int kt = 0; kt < 4; ++kt) {
                half8 bfr = *(const half8*)&w2sh[(nt * 4 + kt) * 512 + lane * 8];
                a = __builtin_amdgcn_mfma_f32_16x16x32_f16(a2[kt], bfr, a, 0, 0, 0);
            }
            float bbv = b2[nt * 16 + n_in];
#pragma unroll
            for (int r = 0; r < 4; ++r) {
                float v = a[r] + bbv;
                st2[wave][quad * 4 + r][nt * 16 + n_in] = (_Float16)(v > 0.f ? v : 0.f);
            }
        }

        float p = 0.0f;
#pragma unroll
        for (int e = 0; e < 16; ++e)
            p += (float)st2[wave][n_in][quad * 16 + e] * w3[quad * 16 + e];
        p += __shfl_down(p, 32);
        p += __shfl_down(p, 16);
        if (quad == 0) out[tok0 + n_in] = p + b3[0];
    };

    compute(bufA, ch0);
    compute(bufB, ch1);
    compute(bufC, ch2);
#undef MLP_LOAD
}

extern "C" void kernel_launch(void* const* d_in, const int* in_sizes, int n_in,
                              void* d_out, int out_size, void* d_ws, size_t ws_size,
                              hipStream_t stream) {
    const float* x     = (const float*)d_in[0];
    const float* w_ih  = (const float*)d_in[1];
    const float* w_hh  = (const float*)d_in[2];
    const float* b_ih  = (const float*)d_in[3];
    const float* b_hh  = (const float*)d_in[4];
    const float* fc1_w = (const float*)d_in[5];
    const float* fc1_b = (const float*)d_in[6];
    const float* fc2_w = (const float*)d_in[7];
    const float* fc2_b = (const float*)d_in[8];
    const float* fc3_w = (const float*)d_in[9];
    const float* fc3_b = (const float*)d_in[10];

    char* ws = (char*)d_ws;
    _Float16* wsw  = (_Float16*)(ws + WSW_OFF);
    float*    bias = (float*)(ws + BIAS_OFF);
    _Float16* hhist= (_Float16*)(ws + HH_OFF);
    unsigned long long* xbuf = (unsigned long long*)(ws + XBUF_OFF);

    k_prep<<<148, 256, 0, stream>>>(w_hh, w_ih, b_ih, b_hh, wsw, bias);
    k_lstm17<<<256, 512, 0, stream>>>(x, wsw, bias, (unsigned*)hhist, xbuf);
    k_mlp6<<<224, 512, 0, stream>>>(hhist, fc1_w, fc2_w, fc1_b, fc2_b,
                                    fc3_w, fc3_b, (float*)d_out);
}